// Round 1
// baseline (86.249 us; speedup 1.0000x reference)
//
#include <hip/hip_runtime.h>

// 4-qubit, 2-layer QML circuit, B=1M samples.
// State: 16 complex amps per sample, held in registers, one thread/sample.
// Flat amp index n = q0*8 + q1*4 + q2*2 + q3 (qubit 0 = bit 3).
//
// Per layer: RX(x_i) on each qubit (per-sample), RY(w0)/RZ(w1) per qubit
// (shared), CNOT chain (0,1)(1,2)(2,3).
//
// Layer 1 on |0000>: product state. v_i = RZ*RY*RX|0> = c_i*P + s_i*Q (comp 0)
//                                                    = c_i*R + s_i*S (comp 1)
// with P,Q,R,S weight-only constants. Expand tensor product -> 16 amps.
// Layer 2: fused U_i = A_i * RX(c_i,s_i), A = RZ*RY weight-only.
// Weight-only constants precomputed by a tiny kernel into d_ws (64 floats).

struct C2 { float r, i; };

__device__ __forceinline__ C2 cmul(C2 a, C2 b) {
    C2 o;
    o.r = a.r * b.r - a.i * b.i;
    o.i = a.r * b.i + a.i * b.r;
    return o;
}

// ---- precompute weight-only gate constants ----
// layout (float g[64]):
//  l=0 qubit q: g[q*8 + 0..7] = Pr,Pi,Qr,Qi,Rr,Ri,Sr,Si
//  l=1 qubit q: g[32 + q*8 + 0..7] = A00r,A00i,A01r,A01i,A10r,A10i,A11r,A11i
__global__ void precompute_gates(const float* __restrict__ w, float* __restrict__ g) {
    int t = threadIdx.x;  // 0..7 -> l*4 + q
    if (t >= 8) return;
    int l = t >> 2, q = t & 3;
    float thy = w[l * 8 + q * 2 + 0];
    float thz = w[l * 8 + q * 2 + 1];
    float cy = cosf(0.5f * thy), sy = sinf(0.5f * thy);
    float cz = cosf(0.5f * thz), sz = sinf(0.5f * thz);
    float* o = g + l * 32 + q * 8;
    if (l == 0) {
        // v0 = c*P + s*Q ; v1 = c*R + s*S
        // P = em*cy, Q = i*em*sy, R = ep*sy, S = -i*ep*cy ; em = (cz,-sz), ep = (cz,sz)
        o[0] = cz * cy;  o[1] = -sz * cy;
        o[2] = sz * sy;  o[3] =  cz * sy;
        o[4] = cz * sy;  o[5] =  sz * sy;
        o[6] = sz * cy;  o[7] = -cz * cy;
    } else {
        // A = RZ*RY = [[em*cy, -em*sy],[ep*sy, ep*cy]]
        o[0] =  cz * cy;  o[1] = -sz * cy;   // A00
        o[2] = -cz * sy;  o[3] =  sz * sy;   // A01
        o[4] =  cz * sy;  o[5] =  sz * sy;   // A10
        o[6] =  cz * cy;  o[7] =  sz * cy;   // A11
    }
}

__device__ __forceinline__ void cnot_chain(C2 st[16]) {
    // CNOT(0,1): q0=1 -> flip q1: swap n=8..11 <-> 12..15
    #pragma unroll
    for (int j = 0; j < 4; j++) { C2 t = st[8 + j]; st[8 + j] = st[12 + j]; st[12 + j] = t; }
    // CNOT(1,2): q1=1 -> flip q2: swap (4,6),(5,7),(12,14),(13,15)
    {
        C2 t;
        t = st[4];  st[4]  = st[6];  st[6]  = t;
        t = st[5];  st[5]  = st[7];  st[7]  = t;
        t = st[12]; st[12] = st[14]; st[14] = t;
        t = st[13]; st[13] = st[15]; st[15] = t;
    }
    // CNOT(2,3): q2=1 -> flip q3: swap (2,3),(6,7),(10,11),(14,15)
    {
        C2 t;
        t = st[2];  st[2]  = st[3];  st[3]  = t;
        t = st[6];  st[6]  = st[7];  st[7]  = t;
        t = st[10]; st[10] = st[11]; st[11] = t;
        t = st[14]; st[14] = st[15]; st[15] = t;
    }
}

__global__ void __launch_bounds__(256) qml_kernel(
        const float* __restrict__ x, const float* __restrict__ g,
        float* __restrict__ out, int batch) {
    int tid = blockIdx.x * blockDim.x + threadIdx.x;
    if (tid >= batch) return;

    float4 xv = reinterpret_cast<const float4*>(x)[tid];
    float c[4], s[4];
    __sincosf(0.5f * xv.x, &s[0], &c[0]);
    __sincosf(0.5f * xv.y, &s[1], &c[1]);
    __sincosf(0.5f * xv.z, &s[2], &c[2]);
    __sincosf(0.5f * xv.w, &s[3], &c[3]);

    // ---- layer 1: product state, per-qubit 2-vectors ----
    C2 v[4][2];
    #pragma unroll
    for (int q = 0; q < 4; q++) {
        const float* o = g + q * 8;
        v[q][0].r = c[q] * o[0] + s[q] * o[2];
        v[q][0].i = c[q] * o[1] + s[q] * o[3];
        v[q][1].r = c[q] * o[4] + s[q] * o[6];
        v[q][1].i = c[q] * o[5] + s[q] * o[7];
    }

    // ---- tensor expansion to 16 amps ----
    C2 t01[4], t23[4], st[16];
    #pragma unroll
    for (int a = 0; a < 2; a++)
        #pragma unroll
        for (int b = 0; b < 2; b++) {
            t01[a * 2 + b] = cmul(v[0][a], v[1][b]);
            t23[a * 2 + b] = cmul(v[2][a], v[3][b]);
        }
    #pragma unroll
    for (int a = 0; a < 4; a++)
        #pragma unroll
        for (int b = 0; b < 4; b++)
            st[a * 4 + b] = cmul(t01[a], t23[b]);

    cnot_chain(st);

    // ---- layer 2: fused U = A * RX per qubit ----
    #pragma unroll
    for (int q = 0; q < 4; q++) {
        const float* o = g + 32 + q * 8;
        C2 u00, u01, u10, u11;
        u00.r = c[q] * o[0] + s[q] * o[3];
        u00.i = c[q] * o[1] - s[q] * o[2];
        u01.r = c[q] * o[2] + s[q] * o[1];
        u01.i = c[q] * o[3] - s[q] * o[0];
        u10.r = c[q] * o[4] + s[q] * o[7];
        u10.i = c[q] * o[5] - s[q] * o[6];
        u11.r = c[q] * o[6] + s[q] * o[5];
        u11.i = c[q] * o[7] - s[q] * o[4];
        int bit = 8 >> q;
        #pragma unroll
        for (int n0 = 0; n0 < 16; n0++) {
            if (n0 & bit) continue;
            int n1 = n0 | bit;
            C2 a0 = st[n0], a1 = st[n1];
            st[n0].r = u00.r * a0.r - u00.i * a0.i + u01.r * a1.r - u01.i * a1.i;
            st[n0].i = u00.r * a0.i + u00.i * a0.r + u01.r * a1.i + u01.i * a1.r;
            st[n1].r = u10.r * a0.r - u10.i * a0.i + u11.r * a1.r - u11.i * a1.i;
            st[n1].i = u10.r * a0.i + u10.i * a0.r + u11.r * a1.i + u11.i * a1.r;
        }
    }

    cnot_chain(st);

    // ---- probabilities and <Z_i> ----
    float p[16];
    #pragma unroll
    for (int n = 0; n < 16; n++) p[n] = st[n].r * st[n].r + st[n].i * st[n].i;

    float a8[8], z3 = 0.f;
    #pragma unroll
    for (int m = 0; m < 8; m++) { a8[m] = p[2 * m] + p[2 * m + 1]; z3 += p[2 * m] - p[2 * m + 1]; }
    float b4[4], z2 = 0.f;
    #pragma unroll
    for (int k = 0; k < 4; k++) { b4[k] = a8[2 * k] + a8[2 * k + 1]; z2 += a8[2 * k] - a8[2 * k + 1]; }
    float z1 = (b4[0] - b4[1]) + (b4[2] - b4[3]);
    float z0 = (b4[0] + b4[1]) - (b4[2] + b4[3]);

    float4 ov = make_float4(z0, z1, z2, z3);
    reinterpret_cast<float4*>(out)[tid] = ov;
}

extern "C" void kernel_launch(void* const* d_in, const int* in_sizes, int n_in,
                              void* d_out, int out_size, void* d_ws, size_t ws_size,
                              hipStream_t stream) {
    const float* x = (const float*)d_in[0];      // [B,4]
    const float* w = (const float*)d_in[1];      // [2,4,2]
    float* out = (float*)d_out;                  // [B,4]
    float* g = (float*)d_ws;                     // 64 floats of gate constants
    int batch = in_sizes[0] / 4;

    precompute_gates<<<1, 64, 0, stream>>>(w, g);
    int block = 256;
    int grid = (batch + block - 1) / block;
    qml_kernel<<<grid, block, 0, stream>>>(x, g, out, batch);
}